// Round 2
// baseline (56.909 us; speedup 1.0000x reference)
//
#include <hip/hip_runtime.h>
#include <math.h>

// InfoNCE: features (4096, 2048, 4) fp32.
// g=1024 groups, ni=4, t=4, n=16 rows/group, c=2048.
// f[g, j, c] = features[g*4 + (j%4), c, j/4]  -> float4 at (b_row, c) holds
// elements of rows {0,4,8,12}+ (j%4) for component t = j/4.
//
// Kernel 1: one block (128 thr) per group. Each thread strides c, loads the
// 4 b-rows' float4 at that c (perfectly coalesced, each byte read once),
// accumulates the 136 unique Gram entries S[i<=j] in registers, butterfly-
// reduces per wave, combines 2 waves in LDS, then 16 threads do the InfoNCE
// epilogue and write the per-group loss-sum to d_ws.
// Kernel 2: deterministic tree-reduce of the 1024 partials -> out = -sum/48.

#define NGROUP 1024
#define C 2048
#define NPAIR 136  // 16*17/2

__device__ __forceinline__ constexpr int pair_idx(int i, int j) {
    // upper triangle, row-major: offset(i) = 16*i - i*(i-1)/2, + (j-i)
    return i * 16 - (i * (i - 1)) / 2 + (j - i);
}

__global__ __launch_bounds__(128, 2)
void infonce_group_kernel(const float4* __restrict__ feats,
                          float* __restrict__ gloss) {
    const int g    = blockIdx.x;
    const int tid  = threadIdx.x;
    const int lane = tid & 63;
    const int wid  = tid >> 6;

    float acc[NPAIR];
#pragma unroll
    for (int p = 0; p < NPAIR; ++p) acc[p] = 0.f;

    const float4* base = feats + (size_t)g * 4 * C;

    for (int it = 0; it < C / 128; ++it) {
        const int c = tid + it * 128;
        const float4 v0 = base[0 * C + c];
        const float4 v1 = base[1 * C + c];
        const float4 v2 = base[2 * C + c];
        const float4 v3 = base[3 * C + c];
        // r[i] = value of output row i at this c; i%4 = b-row, i/4 = t comp
        const float r[16] = { v0.x, v1.x, v2.x, v3.x,
                              v0.y, v1.y, v2.y, v3.y,
                              v0.z, v1.z, v2.z, v3.z,
                              v0.w, v1.w, v2.w, v3.w };
#pragma unroll
        for (int i = 0; i < 16; ++i)
#pragma unroll
            for (int j = i; j < 16; ++j)
                acc[pair_idx(i, j)] = fmaf(r[i], r[j], acc[pair_idx(i, j)]);
    }

    // wave-level butterfly reduce: every lane ends with the wave total
#pragma unroll
    for (int p = 0; p < NPAIR; ++p) {
        float v = acc[p];
        v += __shfl_xor(v, 1);
        v += __shfl_xor(v, 2);
        v += __shfl_xor(v, 4);
        v += __shfl_xor(v, 8);
        v += __shfl_xor(v, 16);
        v += __shfl_xor(v, 32);
        acc[p] = v;
    }

    __shared__ float wsum[2][NPAIR];
    __shared__ float S[16][17];
    __shared__ float rowloss[16];

    // lane-sliced static writes (each p written by exactly one lane per wave)
#pragma unroll
    for (int p = 0; p < NPAIR; ++p) {
        if (lane == (p & 63)) wsum[wid][p] = acc[p];
    }
    __syncthreads();

    // NPAIR=136 > 128 threads: stride the fill (bug fix from last round)
    for (int p = tid; p < NPAIR; p += 128) {
        int i = 0, rem = p;
        while (rem >= 16 - i) { rem -= 16 - i; ++i; }
        const int j = i + rem;
        const float s = wsum[0][p] + wsum[1][p];
        S[i][j] = s;
        S[j][i] = s;
    }
    __syncthreads();

    if (tid < 16) {
        const int i = tid;
        const float inv_i = 1.0f / fmaxf(sqrtf(S[i][i]), 1e-12f);
        float logits_row[16];
        float expneg = 0.f;
#pragma unroll
        for (int j = 0; j < 16; ++j) {
            const float inv_j = 1.0f / fmaxf(sqrtf(S[j][j]), 1e-12f);
            const float cosv = S[i][j] * inv_i * inv_j;
            const float lg = cosv / 0.07f;
            logits_row[j] = lg;
            if ((j >> 2) != (i >> 2)) expneg += expf(lg);  // negatives
        }
        float sum = 0.f;
#pragma unroll
        for (int j = 0; j < 16; ++j) {
            if ((j >> 2) == (i >> 2) && j != i) {          // positives
                const float lg = logits_row[j];
                sum += lg - logf(expneg + expf(lg));
            }
        }
        rowloss[i] = sum;
    }
    __syncthreads();

    if (tid == 0) {
        float t = 0.f;
#pragma unroll
        for (int i = 0; i < 16; ++i) t += rowloss[i];
        gloss[g] = t;
    }
}

__global__ void infonce_final_reduce(const float* __restrict__ gloss,
                                     float* __restrict__ out) {
    const int tid = threadIdx.x;
    float s = 0.f;
    for (int i = tid; i < NGROUP; i += 256) s += gloss[i];
    s += __shfl_xor(s, 1);
    s += __shfl_xor(s, 2);
    s += __shfl_xor(s, 4);
    s += __shfl_xor(s, 8);
    s += __shfl_xor(s, 16);
    s += __shfl_xor(s, 32);
    __shared__ float ws[4];
    const int lane = tid & 63, wid = tid >> 6;
    if (lane == 0) ws[wid] = s;
    __syncthreads();
    if (tid == 0) {
        const float t = ws[0] + ws[1] + ws[2] + ws[3];
        out[0] = -t / 48.0f;
    }
}

extern "C" void kernel_launch(void* const* d_in, const int* in_sizes, int n_in,
                              void* d_out, int out_size, void* d_ws, size_t ws_size,
                              hipStream_t stream) {
    const float4* feats = (const float4*)d_in[0];
    float* gloss = (float*)d_ws;            // 1024 floats scratch
    float* out = (float*)d_out;             // 1 float

    infonce_group_kernel<<<NGROUP, 128, 0, stream>>>(feats, gloss);
    infonce_final_reduce<<<1, 256, 0, stream>>>(gloss, out);
}